// Round 13
// baseline (627.570 us; speedup 1.0000x reference)
//
#include <hip/hip_runtime.h>
#include <math.h>

#define N_NODES 20000
#define N_EDGES 320000
#define N_GRAPHS 32
#define CDIM 256
#define IN_DIMV 739
#define KPAD_DENSE 768
#define ED_DIM 518
#define NLAYERS 4
#define LN_EPS 1e-5f
#define SCAN_BLOCKS ((N_NODES + 255) / 256)  // 79

typedef _Float16 f16x8 __attribute__((ext_vector_type(8)));
typedef _Float16 f16x4 __attribute__((ext_vector_type(4)));
typedef float f32x4 __attribute__((ext_vector_type(4)));

__device__ __forceinline__ float gelu_exact(float x) {
    return 0.5f * x * (1.f + erff(x * 0.7071067811865475f));
}

// ---- merged setup: zero deg | precompute cw/SgSb | prep dense W | prep sq W |
//      zero sdot | zero ns ----
// block ranges: [0,79) zero deg; [79,83) precompute; [83,275) dense W;
// [275,787) square W; [787,866) zero sdot; [866,1804) zero ns.
__global__ __launch_bounds__(256)
void prep_all(const float* __restrict__ ln1_g, const float* __restrict__ ln1_b,
              const float* __restrict__ w1_w, float* __restrict__ cw,
              float* __restrict__ SgSb,
              const float* __restrict__ dense_w, _Float16* __restrict__ wt_dense,
              const float* __restrict__ d1_w, const float* __restrict__ d2_w,
              _Float16* __restrict__ wt_sq, int* __restrict__ deg,
              float* __restrict__ sdot, float* __restrict__ ns) {
    __shared__ float smem[2048 + 64];
    int b = blockIdx.x, tid = threadIdx.x;
    if (b < 79) {
        int i = b * 256 + tid;
        if (i < N_NODES) deg[i] = 0;
    } else if (b < 83) {
        int l = b - 79;
        float sg[4] = {0, 0, 0, 0}, sb[4] = {0, 0, 0, 0};
        for (int i = tid; i < ED_DIM; i += 256) {
            float g = ln1_g[l * ED_DIM + i];
            float bb = ln1_b[l * ED_DIM + i];
            float4 w = *(const float4*)&w1_w[(size_t)(l * ED_DIM + i) * 4];
            float4 c = make_float4(g * w.x, g * w.y, g * w.z, g * w.w);
            *(float4*)&cw[(size_t)(l * ED_DIM + i) * 4] = c;
            sg[0] += c.x; sg[1] += c.y; sg[2] += c.z; sg[3] += c.w;
            sb[0] += bb * w.x; sb[1] += bb * w.y; sb[2] += bb * w.z; sb[3] += bb * w.w;
        }
        for (int c = 0; c < 4; c++) { smem[tid * 8 + c] = sg[c]; smem[tid * 8 + 4 + c] = sb[c]; }
        __syncthreads();
        for (int s = 128; s > 0; s >>= 1) {
            if (tid < s)
                for (int c = 0; c < 8; c++) smem[tid * 8 + c] += smem[(tid + s) * 8 + c];
            __syncthreads();
        }
        if (tid < 8) SgSb[l * 8 + tid] = smem[tid];
    } else if (b < 275) {
        int q = b - 83;
        int kt = q >> 3, nt = q & 7;
        int i = tid >> 5, j = tid & 31;
        float* T = smem;  // [32][33]
#pragma unroll
        for (int ii = 0; ii < 4; ii++) {
            int k = kt * 32 + i + ii * 8;
            T[(i + ii * 8) * 33 + j] = (k < IN_DIMV) ? dense_w[(size_t)k * 256 + nt * 32 + j] : 0.f;
        }
        __syncthreads();
#pragma unroll
        for (int ii = 0; ii < 4; ii++) {
            int n = nt * 32 + i + ii * 8;
            wt_dense[(size_t)n * KPAD_DENSE + kt * 32 + j] = (_Float16)T[j * 33 + i + ii * 8];
        }
    } else if (b < 787) {
        int q = b - 275;
        int z = q >> 6, kt = (q >> 3) & 7, nt = q & 7;
        const float* W = (z < 4) ? d1_w + (size_t)z * 65536 : d2_w + (size_t)(z - 4) * 65536;
        _Float16* O = wt_sq + (size_t)z * 65536;
        int i = tid >> 5, j = tid & 31;
        float* T = smem;
#pragma unroll
        for (int ii = 0; ii < 4; ii++)
            T[(i + ii * 8) * 33 + j] = W[(size_t)(kt * 32 + i + ii * 8) * 256 + nt * 32 + j];
        __syncthreads();
#pragma unroll
        for (int ii = 0; ii < 4; ii++)
            O[(size_t)(nt * 32 + i + ii * 8) * 256 + kt * 32 + j] = (_Float16)T[j * 33 + i + ii * 8];
    } else if (b < 866) {
        int i = (b - 787) * 256 + tid;
        if (i < N_NODES) sdot[i] = 0.f;
    } else {
        int i = (b - 866) * 256 + tid;
        if (i < N_NODES * 12) ns[i] = 0.f;
    }
}

// ---- CSR build ----
__global__ void hist_gstart_kernel(const int* __restrict__ ei, const int* __restrict__ batch,
                                   int* __restrict__ deg, int* __restrict__ gstart) {
    int e = blockIdx.x * 256 + threadIdx.x;
    if (e < N_EDGES) atomicAdd(&deg[ei[N_EDGES + e]], 1);
    if (e < N_NODES) {
        int b = batch[e];
        int bprev = (e == 0) ? -1 : batch[e - 1];
        for (int g = bprev + 1; g <= b; g++) gstart[g] = e;
        if (e == N_NODES - 1)
            for (int g = b + 1; g <= N_GRAPHS; g++) gstart[g] = N_NODES;
    }
}

__global__ __launch_bounds__(256)
void scan1_kernel(const int* __restrict__ deg, int* __restrict__ bsum) {
    __shared__ int red[256];
    int t = threadIdx.x;
    int i = blockIdx.x * 256 + t;
    red[t] = (i < N_NODES) ? deg[i] : 0;
    __syncthreads();
    for (int s = 128; s > 0; s >>= 1) {
        if (t < s) red[t] += red[t + s];
        __syncthreads();
    }
    if (t == 0) bsum[blockIdx.x] = red[0];
}

__global__ __launch_bounds__(128)
void scan2_kernel(const int* __restrict__ bsum, int* __restrict__ boff) {
    __shared__ int s[128];
    int t = threadIdx.x;
    int v = (t < SCAN_BLOCKS) ? bsum[t] : 0;
    s[t] = v;
    __syncthreads();
    for (int off = 1; off < 128; off <<= 1) {
        int o = (t >= off) ? s[t - off] : 0;
        __syncthreads();
        s[t] += o;
        __syncthreads();
    }
    if (t < SCAN_BLOCKS) boff[t] = s[t] - v;  // exclusive
}

__global__ __launch_bounds__(256)
void scan3_kernel(const int* __restrict__ deg, const int* __restrict__ boff,
                  int* __restrict__ row_start, int* __restrict__ cursor) {
    __shared__ int s[256];
    int t = threadIdx.x;
    int i = blockIdx.x * 256 + t;
    int v = (i < N_NODES) ? deg[i] : 0;
    s[t] = v;
    __syncthreads();
    for (int off = 1; off < 256; off <<= 1) {
        int o = (t >= off) ? s[t - off] : 0;
        __syncthreads();
        s[t] += o;
        __syncthreads();
    }
    int base = boff[blockIdx.x];
    int excl = base + s[t] - v;
    if (i < N_NODES) {
        row_start[i] = excl;
        cursor[i] = excl;
    }
    if (i == N_NODES - 1) row_start[N_NODES] = base + s[t];
}

__global__ void scatter_kernel(const int* __restrict__ ei, int* __restrict__ cursor,
                               int* __restrict__ csr_src, int* __restrict__ slot) {
    int e = blockIdx.x * 256 + threadIdx.x;
    if (e < N_EDGES) {
        int d = ei[N_EDGES + e];
        int pos = atomicAdd(&cursor[d], 1);
        csr_src[pos] = ei[e];
        slot[e] = pos;
    }
}

// Dense GEMM: C[M,256] = A[M,739]fp32 @ Wt^T + bias.
// Wave-contiguous A staging: wave w, iter i loads row (w + i*4), k = lane —
// each load instruction covers 256 B contiguous; LDS store 128 B contiguous.
__global__ __launch_bounds__(256)
void gemm_dense(const float* __restrict__ A, const _Float16* __restrict__ Bt,
                const float* __restrict__ bias, _Float16* __restrict__ C) {
    __shared__ __align__(16) _Float16 As[32 * 72];
    __shared__ __align__(16) _Float16 Bs[128 * 72];
    int tid = threadIdx.x;
    int row0 = blockIdx.x * 32;
    int col0 = blockIdx.y * 128;
    int wave = tid >> 6, lane = tid & 63;
    int quad = lane >> 4, lrow = lane & 15;
    int wrow = wave >> 1, wcol = wave & 1;

    int br = tid >> 1, bh = (tid & 1) * 32;
    const _Float16* Brow = &Bt[(size_t)(col0 + br) * KPAD_DENSE];

    const int ntiles = KPAD_DENSE >> 6;  // 12
    float a_f[8];
#pragma unroll
    for (int i = 0; i < 8; i++) {
        int gk = lane;  // k0 = 0
        a_f[i] = (gk < IN_DIMV) ? A[(size_t)(row0 + wave + i * 4) * IN_DIMV + gk] : 0.f;
    }
    uint4 b_raw0 = *(const uint4*)&Brow[bh];
    uint4 b_raw1 = *(const uint4*)&Brow[bh + 8];
    uint4 b_raw2 = *(const uint4*)&Brow[bh + 16];
    uint4 b_raw3 = *(const uint4*)&Brow[bh + 24];

    f32x4 acc[4];
#pragma unroll
    for (int t = 0; t < 4; t++) acc[t] = (f32x4){0.f, 0.f, 0.f, 0.f};

    for (int kt = 0; kt < ntiles; ++kt) {
#pragma unroll
        for (int i = 0; i < 8; i++)
            As[(wave + i * 4) * 72 + lane] = (_Float16)a_f[i];
        *(uint4*)&Bs[br * 72 + bh] = b_raw0;
        *(uint4*)&Bs[br * 72 + bh + 8] = b_raw1;
        *(uint4*)&Bs[br * 72 + bh + 16] = b_raw2;
        *(uint4*)&Bs[br * 72 + bh + 24] = b_raw3;
        __syncthreads();

        if (kt + 1 < ntiles) {
            int k0 = (kt + 1) << 6;
            int gk = k0 + lane;
            bool ok = gk < IN_DIMV;
#pragma unroll
            for (int i = 0; i < 8; i++)
                a_f[i] = ok ? A[(size_t)(row0 + wave + i * 4) * IN_DIMV + gk] : 0.f;
            b_raw0 = *(const uint4*)&Brow[k0 + bh];
            b_raw1 = *(const uint4*)&Brow[k0 + bh + 8];
            b_raw2 = *(const uint4*)&Brow[k0 + bh + 16];
            b_raw3 = *(const uint4*)&Brow[k0 + bh + 24];
        }

#pragma unroll
        for (int h = 0; h < 2; h++) {
            f16x8 af = *(const f16x8*)&As[(wrow * 16 + lrow) * 72 + h * 32 + quad * 8];
#pragma unroll
            for (int t = 0; t < 4; t++) {
                f16x8 bf = *(const f16x8*)&Bs[((wcol * 4 + t) * 16 + lrow) * 72 + h * 32 + quad * 8];
                acc[t] = __builtin_amdgcn_mfma_f32_16x16x32_f16(af, bf, acc[t], 0, 0, 0);
            }
        }
        __syncthreads();
    }

    int orow = row0 + wrow * 16 + quad * 4;
#pragma unroll
    for (int t = 0; t < 4; t++) {
        int col = col0 + (wcol * 4 + t) * 16 + lrow;
        float bv = bias[col];
#pragma unroll
        for (int r = 0; r < 4; r++)
            C[(size_t)(orow + r) * 256 + col] = (_Float16)(acc[t][r] + bv);
    }
}

// Square GEMM. MODE 0: gelu + C-write. MODE 1 (d1): gelu + C-write + fused
// node-summary accumulation into ns (P1,P2,Q1,Q2 via lrow-reduce + atomicAdd).
// MODE 2 (final d2): gelu + head_w dot into sdot, no C-write.
template <int MODE>
__global__ __launch_bounds__(256)
void gemm_mfma(const _Float16* __restrict__ A, const _Float16* __restrict__ Bt,
               const float* __restrict__ bias, _Float16* __restrict__ C,
               const float* __restrict__ aux, float* __restrict__ outv) {
    __shared__ __align__(16) _Float16 As[32 * 72];
    __shared__ __align__(16) _Float16 Bs[128 * 72];
    int tid = threadIdx.x;
    int row0 = blockIdx.x * 32;
    int col0 = blockIdx.y * 128;
    int wave = tid >> 6, lane = tid & 63;
    int quad = lane >> 4, lrow = lane & 15;
    int wrow = wave >> 1, wcol = wave & 1;

    int ar = tid >> 3, ak8 = (tid & 7) * 8;
    int br = tid >> 1, bh = (tid & 1) * 32;

    const _Float16* Arow = &A[(size_t)(row0 + ar) * CDIM];
    const _Float16* Brow = &Bt[(size_t)(col0 + br) * CDIM];

    const int ntiles = CDIM >> 6;  // 4
    uint4 a_raw = *(const uint4*)&Arow[ak8];
    uint4 b_raw0 = *(const uint4*)&Brow[bh];
    uint4 b_raw1 = *(const uint4*)&Brow[bh + 8];
    uint4 b_raw2 = *(const uint4*)&Brow[bh + 16];
    uint4 b_raw3 = *(const uint4*)&Brow[bh + 24];

    f32x4 acc[4];
#pragma unroll
    for (int t = 0; t < 4; t++) acc[t] = (f32x4){0.f, 0.f, 0.f, 0.f};

    for (int kt = 0; kt < ntiles; ++kt) {
        *(uint4*)&As[ar * 72 + ak8] = a_raw;
        *(uint4*)&Bs[br * 72 + bh] = b_raw0;
        *(uint4*)&Bs[br * 72 + bh + 8] = b_raw1;
        *(uint4*)&Bs[br * 72 + bh + 16] = b_raw2;
        *(uint4*)&Bs[br * 72 + bh + 24] = b_raw3;
        __syncthreads();

        if (kt + 1 < ntiles) {
            int k0 = (kt + 1) << 6;
            a_raw = *(const uint4*)&Arow[k0 + ak8];
            b_raw0 = *(const uint4*)&Brow[k0 + bh];
            b_raw1 = *(const uint4*)&Brow[k0 + bh + 8];
            b_raw2 = *(const uint4*)&Brow[k0 + bh + 16];
            b_raw3 = *(const uint4*)&Brow[k0 + bh + 24];
        }

#pragma unroll
        for (int h = 0; h < 2; h++) {
            f16x8 af = *(const f16x8*)&As[(wrow * 16 + lrow) * 72 + h * 32 + quad * 8];
#pragma unroll
            for (int t = 0; t < 4; t++) {
                f16x8 bf = *(const f16x8*)&Bs[((wcol * 4 + t) * 16 + lrow) * 72 + h * 32 + quad * 8];
                acc[t] = __builtin_amdgcn_mfma_f32_16x16x32_f16(af, bf, acc[t], 0, 0, 0);
            }
        }
        __syncthreads();
    }

    int orow = row0 + wrow * 16 + quad * 4;
    if (MODE == 2) {
        float dp[4] = {0.f, 0.f, 0.f, 0.f};
#pragma unroll
        for (int t = 0; t < 4; t++) {
            int col = col0 + (wcol * 4 + t) * 16 + lrow;
            float hw = aux[col];
            float bv = bias[col];
#pragma unroll
            for (int r = 0; r < 4; r++)
                dp[r] += gelu_exact(acc[t][r] + bv) * hw;
        }
#pragma unroll
        for (int r = 0; r < 4; r++) {
#pragma unroll
            for (int off = 1; off < 16; off <<= 1)
                dp[r] += __shfl_xor(dp[r], off, 64);
        }
        if (lrow == 0) {
#pragma unroll
            for (int r = 0; r < 4; r++) atomicAdd(&outv[orow + r], dp[r]);
        }
    } else if (MODE == 1) {
        float p1[4][4], p2[4][4], q1[4], q2[4];
#pragma unroll
        for (int r = 0; r < 4; r++) {
            q1[r] = 0.f; q2[r] = 0.f;
#pragma unroll
            for (int c = 0; c < 4; c++) { p1[r][c] = 0.f; p2[r][c] = 0.f; }
        }
#pragma unroll
        for (int t = 0; t < 4; t++) {
            int col = col0 + (wcol * 4 + t) * 16 + lrow;
            float bv = bias[col];
            float4 c0 = *(const float4*)&aux[(size_t)col * 4];          // cw[col]
            float4 c1 = *(const float4*)&aux[(size_t)(256 + col) * 4];  // cw[256+col]
#pragma unroll
            for (int r = 0; r < 4; r++) {
                float v = gelu_exact(acc[t][r] + bv);
                C[(size_t)(orow + r) * 256 + col] = (_Float16)v;
                q1[r] += v; q2[r] += v * v;
                p1[r][0] += v * c0.x; p1[r][1] += v * c0.y;
                p1[r][2] += v * c0.z; p1[r][3] += v * c0.w;
                p2[r][0] += v * c1.x; p2[r][1] += v * c1.y;
                p2[r][2] += v * c1.z; p2[r][3] += v * c1.w;
            }
        }
#pragma unroll
        for (int off = 1; off < 16; off <<= 1) {
#pragma unroll
            for (int r = 0; r < 4; r++) {
                q1[r] += __shfl_xor(q1[r], off, 64);
                q2[r] += __shfl_xor(q2[r], off, 64);
#pragma unroll
                for (int c = 0; c < 4; c++) {
                    p1[r][c] += __shfl_xor(p1[r][c], off, 64);
                    p2[r][c] += __shfl_xor(p2[r][c], off, 64);
                }
            }
        }
        if (lrow == 0) {
#pragma unroll
            for (int r = 0; r < 4; r++) {
                float* p = &outv[(size_t)(orow + r) * 12];
#pragma unroll
                for (int c = 0; c < 4; c++) {
                    atomicAdd(p + c, p1[r][c]);
                    atomicAdd(p + 4 + c, p2[r][c]);
                }
                atomicAdd(p + 8, q1[r]);
                atomicAdd(p + 9, q2[r]);
            }
        }
    } else {
#pragma unroll
        for (int t = 0; t < 4; t++) {
            int col = col0 + (wcol * 4 + t) * 16 + lrow;
            float bv = bias[col];
#pragma unroll
            for (int r = 0; r < 4; r++)
                C[(size_t)(orow + r) * 256 + col] = (_Float16)gelu_exact(acc[t][r] + bv);
        }
    }
}

// One thread per edge: edge MLP from node summaries; writes w into CSR slot.
__global__ __launch_bounds__(256)
void edge_weight_kernel(const float* __restrict__ ns, const float* __restrict__ x_pos,
                        const int* __restrict__ ei, const float* __restrict__ cw,
                        const float* __restrict__ SgSb, const float* __restrict__ w1_b,
                        const float* __restrict__ ln2_g, const float* __restrict__ ln2_b,
                        const float* __restrict__ w2_w, const float* __restrict__ w2_b,
                        const int* __restrict__ slot, float* __restrict__ w_csr) {
    int e = blockIdx.x * 256 + threadIdx.x;
    if (e >= N_EDGES) return;
    int s = ei[e], d = ei[N_EDGES + e];
    const float* nss = &ns[(size_t)s * 12];
    const float* nsd = &ns[(size_t)d * 12];
    float4 p1 = *(const float4*)nss;
    float4 p2 = *(const float4*)(nsd + 4);
    float S1 = nss[8] + nsd[8];
    float S2 = nss[9] + nsd[9];
    float D[4] = {p1.x + p2.x, p1.y + p2.y, p1.z + p2.z, p1.w + p2.w};
    float ps[6];
    ps[0] = x_pos[(size_t)s * 3 + 0];
    ps[1] = x_pos[(size_t)s * 3 + 1];
    ps[2] = x_pos[(size_t)s * 3 + 2];
    ps[3] = x_pos[(size_t)d * 3 + 0];
    ps[4] = x_pos[(size_t)d * 3 + 1];
    ps[5] = x_pos[(size_t)d * 3 + 2];
#pragma unroll
    for (int k = 0; k < 6; k++) {
        S1 += ps[k];
        S2 += ps[k] * ps[k];
        float4 c = *(const float4*)&cw[(size_t)(512 + k) * 4];
        D[0] += ps[k] * c.x; D[1] += ps[k] * c.y; D[2] += ps[k] * c.z; D[3] += ps[k] * c.w;
    }
    const float inv = 1.f / 518.f;
    float mu = S1 * inv;
    float var = fmaf(-mu, mu, S2 * inv);
    float rstd = rsqrtf(var + LN_EPS);
    float t[4];
#pragma unroll
    for (int c = 0; c < 4; c++)
        t[c] = gelu_exact(rstd * (D[c] - mu * SgSb[c]) + SgSb[4 + c] + w1_b[c]);
    float mu2 = 0.25f * (t[0] + t[1] + t[2] + t[3]);
    float var2 = 0.25f * ((t[0] - mu2) * (t[0] - mu2) + (t[1] - mu2) * (t[1] - mu2) +
                          (t[2] - mu2) * (t[2] - mu2) + (t[3] - mu2) * (t[3] - mu2));
    float r2 = rsqrtf(var2 + LN_EPS);
    float z = w2_b[0];
#pragma unroll
    for (int c = 0; c < 4; c++)
        z += ((t[c] - mu2) * r2 * ln2_g[c] + ln2_b[c]) * w2_w[c];
    w_csr[slot[e]] = 1.f / (1.f + expf(-z));
}

// CSR SpMM over fp16 m, unrolled x8; also zeroes ns[n] for the next layer's
// fused summary accumulation (safe: edge_weight has already read ns).
__global__ __launch_bounds__(256)
void agg_kernel(const _Float16* __restrict__ m, const int* __restrict__ csr_src,
                const float* __restrict__ w_csr, const int* __restrict__ row_start,
                _Float16* __restrict__ agg, float* __restrict__ ns) {
    int n = blockIdx.x * 4 + (threadIdx.x >> 6);
    if (n >= N_NODES) return;
    int lane = threadIdx.x & 63;
    int beg = row_start[n], end = row_start[n + 1];
    float a0 = 0.f, a1 = 0.f, a2 = 0.f, a3 = 0.f;
    int j = beg;
    for (; j + 8 <= end; j += 8) {
        int si[8];
        float wi[8];
#pragma unroll
        for (int u = 0; u < 8; u++) { si[u] = csr_src[j + u]; wi[u] = w_csr[j + u]; }
        f16x4 v[8];
#pragma unroll
        for (int u = 0; u < 8; u++) v[u] = *(const f16x4*)&m[(size_t)si[u] * CDIM + lane * 4];
#pragma unroll
        for (int u = 0; u < 8; u++) {
            a0 = fmaf(wi[u], (float)v[u][0], a0);
            a1 = fmaf(wi[u], (float)v[u][1], a1);
            a2 = fmaf(wi[u], (float)v[u][2], a2);
            a3 = fmaf(wi[u], (float)v[u][3], a3);
        }
    }
    for (; j < end; j++) {
        int s = csr_src[j];
        float w = w_csr[j];
        f16x4 v = *(const f16x4*)&m[(size_t)s * CDIM + lane * 4];
        a0 = fmaf(w, (float)v[0], a0);
        a1 = fmaf(w, (float)v[1], a1);
        a2 = fmaf(w, (float)v[2], a2);
        a3 = fmaf(w, (float)v[3], a3);
    }
    f16x4 o;
    o[0] = (_Float16)a0; o[1] = (_Float16)a1; o[2] = (_Float16)a2; o[3] = (_Float16)a3;
    *(f16x4*)&agg[(size_t)n * CDIM + lane * 4] = o;
    if (lane < 12) ns[(size_t)n * 12 + lane] = 0.f;
}

__global__ __launch_bounds__(256)
void final_head_kernel(const float* __restrict__ sdot, const int* __restrict__ gstart,
                       const float* __restrict__ head_b, float* __restrict__ out) {
    int g = blockIdx.x;
    int t = threadIdx.x;
    int beg = gstart[g], end = gstart[g + 1];
    float s = 0.f;
    for (int i = beg + t; i < end; i += 256) s += sdot[i];
    __shared__ float red[256];
    red[t] = s;
    __syncthreads();
    for (int k = 128; k > 0; k >>= 1) {
        if (t < k) red[t] += red[t + k];
        __syncthreads();
    }
    if (t == 0) out[g] = red[0] / fmaxf((float)(end - beg), 1.f) + head_b[0];
}

extern "C" void kernel_launch(void* const* d_in, const int* in_sizes, int n_in,
                              void* d_out, int out_size, void* d_ws, size_t ws_size,
                              hipStream_t stream) {
    const float* x       = (const float*)d_in[0];
    const float* x_pos   = (const float*)d_in[1];
    const int*   ei      = (const int*)d_in[2];
    const int*   batch   = (const int*)d_in[3];
    const float* dense_w = (const float*)d_in[4];
    const float* dense_b = (const float*)d_in[5];
    const float* d1_w    = (const float*)d_in[6];
    const float* d1_b    = (const float*)d_in[7];
    const float* ln1_g   = (const float*)d_in[8];
    const float* ln1_b   = (const float*)d_in[9];
    const float* w1_w    = (const float*)d_in[10];
    const float* w1_b    = (const float*)d_in[11];
    const float* ln2_g   = (const float*)d_in[12];
    const float* ln2_b   = (const float*)d_in[13];
    const float* w2_w    = (const float*)d_in[14];
    const float* w2_b    = (const float*)d_in[15];
    const float* d2_w    = (const float*)d_in[16];
    const float* d2_b    = (const float*)d_in[17];
    const float* head_w  = (const float*)d_in[18];
    const float* head_b  = (const float*)d_in[19];
    float* out = (float*)d_out;

    _Float16* hbuf0 = (_Float16*)d_ws;                          // [N][256] fp16
    _Float16* hbuf1 = hbuf0 + (size_t)N_NODES * CDIM;           // [N][256] fp16
    _Float16* wt_dense = hbuf1 + (size_t)N_NODES * CDIM;        // [256][768] fp16
    _Float16* wt_sq    = wt_dense + (size_t)256 * KPAD_DENSE;   // [8][256][256] fp16
    float* cw    = (float*)(wt_sq + (size_t)8 * 256 * 256);     // [L][518][4]
    float* SgSb  = cw + (size_t)NLAYERS * ED_DIM * 4;           // [L][8]
    float* ns    = SgSb + NLAYERS * 8;                          // [N][12]
    float* sdot  = ns + (size_t)N_NODES * 12;                   // [N]
    float* w_csr = sdot + N_NODES;                              // [E]
    int* gstart    = (int*)(w_csr + N_EDGES);                   // [33]
    int* deg       = gstart + N_GRAPHS + 1;                     // [N]
    int* row_start = deg + N_NODES;                             // [N+1]
    int* cursor    = row_start + N_NODES + 1;                   // [N]
    int* csr_src   = cursor + N_NODES;                          // [E]
    int* slot      = csr_src + N_EDGES;                         // [E]
    int* bsum      = slot + N_EDGES;                            // [SCAN_BLOCKS]
    int* boff      = bsum + SCAN_BLOCKS;                        // [SCAN_BLOCKS]

    prep_all<<<1804, 256, 0, stream>>>(ln1_g, ln1_b, w1_w, cw, SgSb,
                                       dense_w, wt_dense, d1_w, d2_w, wt_sq, deg, sdot, ns);

    hist_gstart_kernel<<<(N_EDGES + 255) / 256, 256, 0, stream>>>(ei, batch, deg, gstart);
    scan1_kernel<<<SCAN_BLOCKS, 256, 0, stream>>>(deg, bsum);
    scan2_kernel<<<1, 128, 0, stream>>>(bsum, boff);
    scan3_kernel<<<SCAN_BLOCKS, 256, 0, stream>>>(deg, boff, row_start, cursor);
    scatter_kernel<<<(N_EDGES + 255) / 256, 256, 0, stream>>>(ei, cursor, csr_src, slot);

    const dim3 GGRID(N_NODES / 32, 2);  // (625, 2) = 1250 blocks
    gemm_dense<<<GGRID, 256, 0, stream>>>(x, wt_dense, dense_b, hbuf0);

    _Float16* h = hbuf0;
    _Float16* other = hbuf1;
    for (int l = 0; l < NLAYERS; l++) {
        // d1: GEMM + gelu + fused node-summary into ns
        gemm_mfma<1><<<GGRID, 256, 0, stream>>>(
            h, wt_sq + (size_t)l * 65536, d1_b + l * CDIM, other,
            cw + (size_t)l * ED_DIM * 4, ns);
        edge_weight_kernel<<<(N_EDGES + 255) / 256, 256, 0, stream>>>(
            ns, x_pos, ei, cw + (size_t)l * ED_DIM * 4, SgSb + l * 8, w1_b + l * 4,
            ln2_g + l * 4, ln2_b + l * 4, w2_w + l * 4, w2_b + l, slot, w_csr);
        // agg also re-zeroes ns for the next layer
        agg_kernel<<<(N_NODES + 3) / 4, 256, 0, stream>>>(other, csr_src, w_csr, row_start,
                                                          h, ns);
        if (l < NLAYERS - 1) {
            gemm_mfma<0><<<GGRID, 256, 0, stream>>>(
                h, wt_sq + (size_t)(4 + l) * 65536, d2_b + l * CDIM, other, nullptr, nullptr);
        } else {
            gemm_mfma<2><<<GGRID, 256, 0, stream>>>(
                h, wt_sq + (size_t)(4 + l) * 65536, d2_b + l * CDIM, other, head_w, sdot);
        }
        _Float16* tmp = h; h = other; other = tmp;
    }

    final_head_kernel<<<N_GRAPHS, 256, 0, stream>>>(sdot, gstart, head_b, out);
}

// Round 14
// 530.702 us; speedup vs baseline: 1.1825x; 1.1825x over previous
//
#include <hip/hip_runtime.h>
#include <math.h>

#define N_NODES 20000
#define N_EDGES 320000
#define N_GRAPHS 32
#define CDIM 256
#define IN_DIMV 739
#define KPAD_DENSE 768
#define ED_DIM 518
#define NLAYERS 4
#define LN_EPS 1e-5f
#define SCAN_BLOCKS ((N_NODES + 255) / 256)  // 79

typedef _Float16 f16x8 __attribute__((ext_vector_type(8)));
typedef _Float16 f16x4 __attribute__((ext_vector_type(4)));
typedef float f32x4 __attribute__((ext_vector_type(4)));

__device__ __forceinline__ float gelu_exact(float x) {
    return 0.5f * x * (1.f + erff(x * 0.7071067811865475f));
}

// ---- merged setup: zero deg | precompute cw/SgSb | prep dense W | prep sq W | zero sdot ----
// block ranges: [0,79) zero deg; [79,83) precompute; [83,275) dense W;
// [275,787) square W; [787,866) zero sdot.
__global__ __launch_bounds__(256)
void prep_all(const float* __restrict__ ln1_g, const float* __restrict__ ln1_b,
              const float* __restrict__ w1_w, float* __restrict__ cw,
              float* __restrict__ SgSb,
              const float* __restrict__ dense_w, _Float16* __restrict__ wt_dense,
              const float* __restrict__ d1_w, const float* __restrict__ d2_w,
              _Float16* __restrict__ wt_sq, int* __restrict__ deg,
              float* __restrict__ sdot) {
    __shared__ float smem[2048 + 64];
    int b = blockIdx.x, tid = threadIdx.x;
    if (b < 79) {
        int i = b * 256 + tid;
        if (i < N_NODES) deg[i] = 0;
    } else if (b < 83) {
        int l = b - 79;
        float sg[4] = {0, 0, 0, 0}, sb[4] = {0, 0, 0, 0};
        for (int i = tid; i < ED_DIM; i += 256) {
            float g = ln1_g[l * ED_DIM + i];
            float bb = ln1_b[l * ED_DIM + i];
            float4 w = *(const float4*)&w1_w[(size_t)(l * ED_DIM + i) * 4];
            float4 c = make_float4(g * w.x, g * w.y, g * w.z, g * w.w);
            *(float4*)&cw[(size_t)(l * ED_DIM + i) * 4] = c;
            sg[0] += c.x; sg[1] += c.y; sg[2] += c.z; sg[3] += c.w;
            sb[0] += bb * w.x; sb[1] += bb * w.y; sb[2] += bb * w.z; sb[3] += bb * w.w;
        }
        for (int c = 0; c < 4; c++) { smem[tid * 8 + c] = sg[c]; smem[tid * 8 + 4 + c] = sb[c]; }
        __syncthreads();
        for (int s = 128; s > 0; s >>= 1) {
            if (tid < s)
                for (int c = 0; c < 8; c++) smem[tid * 8 + c] += smem[(tid + s) * 8 + c];
            __syncthreads();
        }
        if (tid < 8) SgSb[l * 8 + tid] = smem[tid];
    } else if (b < 275) {
        int q = b - 83;
        int kt = q >> 3, nt = q & 7;
        int i = tid >> 5, j = tid & 31;
        float* T = smem;  // [32][33]
#pragma unroll
        for (int ii = 0; ii < 4; ii++) {
            int k = kt * 32 + i + ii * 8;
            T[(i + ii * 8) * 33 + j] = (k < IN_DIMV) ? dense_w[(size_t)k * 256 + nt * 32 + j] : 0.f;
        }
        __syncthreads();
#pragma unroll
        for (int ii = 0; ii < 4; ii++) {
            int n = nt * 32 + i + ii * 8;
            wt_dense[(size_t)n * KPAD_DENSE + kt * 32 + j] = (_Float16)T[j * 33 + i + ii * 8];
        }
    } else if (b < 787) {
        int q = b - 275;
        int z = q >> 6, kt = (q >> 3) & 7, nt = q & 7;
        const float* W = (z < 4) ? d1_w + (size_t)z * 65536 : d2_w + (size_t)(z - 4) * 65536;
        _Float16* O = wt_sq + (size_t)z * 65536;
        int i = tid >> 5, j = tid & 31;
        float* T = smem;
#pragma unroll
        for (int ii = 0; ii < 4; ii++)
            T[(i + ii * 8) * 33 + j] = W[(size_t)(kt * 32 + i + ii * 8) * 256 + nt * 32 + j];
        __syncthreads();
#pragma unroll
        for (int ii = 0; ii < 4; ii++)
            O[(size_t)(nt * 32 + i + ii * 8) * 256 + kt * 32 + j] = (_Float16)T[j * 33 + i + ii * 8];
    } else {
        int i = (b - 787) * 256 + tid;
        if (i < N_NODES) sdot[i] = 0.f;
    }
}

// ---- CSR build ----
__global__ void hist_gstart_kernel(const int* __restrict__ ei, const int* __restrict__ batch,
                                   int* __restrict__ deg, int* __restrict__ gstart) {
    int e = blockIdx.x * 256 + threadIdx.x;
    if (e < N_EDGES) atomicAdd(&deg[ei[N_EDGES + e]], 1);
    if (e < N_NODES) {
        int b = batch[e];
        int bprev = (e == 0) ? -1 : batch[e - 1];
        for (int g = bprev + 1; g <= b; g++) gstart[g] = e;
        if (e == N_NODES - 1)
            for (int g = b + 1; g <= N_GRAPHS; g++) gstart[g] = N_NODES;
    }
}

__global__ __launch_bounds__(256)
void scan1_kernel(const int* __restrict__ deg, int* __restrict__ bsum) {
    __shared__ int red[256];
    int t = threadIdx.x;
    int i = blockIdx.x * 256 + t;
    red[t] = (i < N_NODES) ? deg[i] : 0;
    __syncthreads();
    for (int s = 128; s > 0; s >>= 1) {
        if (t < s) red[t] += red[t + s];
        __syncthreads();
    }
    if (t == 0) bsum[blockIdx.x] = red[0];
}

__global__ __launch_bounds__(128)
void scan2_kernel(const int* __restrict__ bsum, int* __restrict__ boff) {
    __shared__ int s[128];
    int t = threadIdx.x;
    int v = (t < SCAN_BLOCKS) ? bsum[t] : 0;
    s[t] = v;
    __syncthreads();
    for (int off = 1; off < 128; off <<= 1) {
        int o = (t >= off) ? s[t - off] : 0;
        __syncthreads();
        s[t] += o;
        __syncthreads();
    }
    if (t < SCAN_BLOCKS) boff[t] = s[t] - v;  // exclusive
}

__global__ __launch_bounds__(256)
void scan3_kernel(const int* __restrict__ deg, const int* __restrict__ boff,
                  int* __restrict__ row_start, int* __restrict__ cursor) {
    __shared__ int s[256];
    int t = threadIdx.x;
    int i = blockIdx.x * 256 + t;
    int v = (i < N_NODES) ? deg[i] : 0;
    s[t] = v;
    __syncthreads();
    for (int off = 1; off < 256; off <<= 1) {
        int o = (t >= off) ? s[t - off] : 0;
        __syncthreads();
        s[t] += o;
        __syncthreads();
    }
    int base = boff[blockIdx.x];
    int excl = base + s[t] - v;
    if (i < N_NODES) {
        row_start[i] = excl;
        cursor[i] = excl;
    }
    if (i == N_NODES - 1) row_start[N_NODES] = base + s[t];
}

__global__ void scatter_kernel(const int* __restrict__ ei, int* __restrict__ cursor,
                               int* __restrict__ csr_src, int* __restrict__ slot) {
    int e = blockIdx.x * 256 + threadIdx.x;
    if (e < N_EDGES) {
        int d = ei[N_EDGES + e];
        int pos = atomicAdd(&cursor[d], 1);
        csr_src[pos] = ei[e];
        slot[e] = pos;
    }
}

// Dense GEMM: C[M,256] = A[M,739]fp32 @ Wt^T + bias.
// Wave-contiguous A staging (verified round-13 win): wave w, iter i loads
// row (w + i*4), k = lane — 256 B contiguous per load instruction.
__global__ __launch_bounds__(256)
void gemm_dense(const float* __restrict__ A, const _Float16* __restrict__ Bt,
                const float* __restrict__ bias, _Float16* __restrict__ C) {
    __shared__ __align__(16) _Float16 As[32 * 72];
    __shared__ __align__(16) _Float16 Bs[128 * 72];
    int tid = threadIdx.x;
    int row0 = blockIdx.x * 32;
    int col0 = blockIdx.y * 128;
    int wave = tid >> 6, lane = tid & 63;
    int quad = lane >> 4, lrow = lane & 15;
    int wrow = wave >> 1, wcol = wave & 1;

    int br = tid >> 1, bh = (tid & 1) * 32;
    const _Float16* Brow = &Bt[(size_t)(col0 + br) * KPAD_DENSE];

    const int ntiles = KPAD_DENSE >> 6;  // 12
    float a_f[8];
#pragma unroll
    for (int i = 0; i < 8; i++) {
        int gk = lane;
        a_f[i] = (gk < IN_DIMV) ? A[(size_t)(row0 + wave + i * 4) * IN_DIMV + gk] : 0.f;
    }
    uint4 b_raw0 = *(const uint4*)&Brow[bh];
    uint4 b_raw1 = *(const uint4*)&Brow[bh + 8];
    uint4 b_raw2 = *(const uint4*)&Brow[bh + 16];
    uint4 b_raw3 = *(const uint4*)&Brow[bh + 24];

    f32x4 acc[4];
#pragma unroll
    for (int t = 0; t < 4; t++) acc[t] = (f32x4){0.f, 0.f, 0.f, 0.f};

    for (int kt = 0; kt < ntiles; ++kt) {
#pragma unroll
        for (int i = 0; i < 8; i++)
            As[(wave + i * 4) * 72 + lane] = (_Float16)a_f[i];
        *(uint4*)&Bs[br * 72 + bh] = b_raw0;
        *(uint4*)&Bs[br * 72 + bh + 8] = b_raw1;
        *(uint4*)&Bs[br * 72 + bh + 16] = b_raw2;
        *(uint4*)&Bs[br * 72 + bh + 24] = b_raw3;
        __syncthreads();

        if (kt + 1 < ntiles) {
            int k0 = (kt + 1) << 6;
            int gk = k0 + lane;
            bool ok = gk < IN_DIMV;
#pragma unroll
            for (int i = 0; i < 8; i++)
                a_f[i] = ok ? A[(size_t)(row0 + wave + i * 4) * IN_DIMV + gk] : 0.f;
            b_raw0 = *(const uint4*)&Brow[k0 + bh];
            b_raw1 = *(const uint4*)&Brow[k0 + bh + 8];
            b_raw2 = *(const uint4*)&Brow[k0 + bh + 16];
            b_raw3 = *(const uint4*)&Brow[k0 + bh + 24];
        }

#pragma unroll
        for (int h = 0; h < 2; h++) {
            f16x8 af = *(const f16x8*)&As[(wrow * 16 + lrow) * 72 + h * 32 + quad * 8];
#pragma unroll
            for (int t = 0; t < 4; t++) {
                f16x8 bf = *(const f16x8*)&Bs[((wcol * 4 + t) * 16 + lrow) * 72 + h * 32 + quad * 8];
                acc[t] = __builtin_amdgcn_mfma_f32_16x16x32_f16(af, bf, acc[t], 0, 0, 0);
            }
        }
        __syncthreads();
    }

    int orow = row0 + wrow * 16 + quad * 4;
#pragma unroll
    for (int t = 0; t < 4; t++) {
        int col = col0 + (wcol * 4 + t) * 16 + lrow;
        float bv = bias[col];
#pragma unroll
        for (int r = 0; r < 4; r++)
            C[(size_t)(orow + r) * 256 + col] = (_Float16)(acc[t][r] + bv);
    }
}

// Square GEMM. DOT=false: gelu + C-write. DOT=true (final d2): gelu +
// head_w dot into sdot via quad-shuffle reduce + atomicAdd, no C-write.
template <bool DOT>
__global__ __launch_bounds__(256)
void gemm_mfma(const _Float16* __restrict__ A, const _Float16* __restrict__ Bt,
               const float* __restrict__ bias, _Float16* __restrict__ C,
               const float* __restrict__ head_w, float* __restrict__ sdot) {
    __shared__ __align__(16) _Float16 As[32 * 72];
    __shared__ __align__(16) _Float16 Bs[128 * 72];
    int tid = threadIdx.x;
    int row0 = blockIdx.x * 32;
    int col0 = blockIdx.y * 128;
    int wave = tid >> 6, lane = tid & 63;
    int quad = lane >> 4, lrow = lane & 15;
    int wrow = wave >> 1, wcol = wave & 1;

    int ar = tid >> 3, ak8 = (tid & 7) * 8;
    int br = tid >> 1, bh = (tid & 1) * 32;

    const _Float16* Arow = &A[(size_t)(row0 + ar) * CDIM];
    const _Float16* Brow = &Bt[(size_t)(col0 + br) * CDIM];

    const int ntiles = CDIM >> 6;  // 4
    uint4 a_raw = *(const uint4*)&Arow[ak8];
    uint4 b_raw0 = *(const uint4*)&Brow[bh];
    uint4 b_raw1 = *(const uint4*)&Brow[bh + 8];
    uint4 b_raw2 = *(const uint4*)&Brow[bh + 16];
    uint4 b_raw3 = *(const uint4*)&Brow[bh + 24];

    f32x4 acc[4];
#pragma unroll
    for (int t = 0; t < 4; t++) acc[t] = (f32x4){0.f, 0.f, 0.f, 0.f};

    for (int kt = 0; kt < ntiles; ++kt) {
        *(uint4*)&As[ar * 72 + ak8] = a_raw;
        *(uint4*)&Bs[br * 72 + bh] = b_raw0;
        *(uint4*)&Bs[br * 72 + bh + 8] = b_raw1;
        *(uint4*)&Bs[br * 72 + bh + 16] = b_raw2;
        *(uint4*)&Bs[br * 72 + bh + 24] = b_raw3;
        __syncthreads();

        if (kt + 1 < ntiles) {
            int k0 = (kt + 1) << 6;
            a_raw = *(const uint4*)&Arow[k0 + ak8];
            b_raw0 = *(const uint4*)&Brow[k0 + bh];
            b_raw1 = *(const uint4*)&Brow[k0 + bh + 8];
            b_raw2 = *(const uint4*)&Brow[k0 + bh + 16];
            b_raw3 = *(const uint4*)&Brow[k0 + bh + 24];
        }

#pragma unroll
        for (int h = 0; h < 2; h++) {
            f16x8 af = *(const f16x8*)&As[(wrow * 16 + lrow) * 72 + h * 32 + quad * 8];
#pragma unroll
            for (int t = 0; t < 4; t++) {
                f16x8 bf = *(const f16x8*)&Bs[((wcol * 4 + t) * 16 + lrow) * 72 + h * 32 + quad * 8];
                acc[t] = __builtin_amdgcn_mfma_f32_16x16x32_f16(af, bf, acc[t], 0, 0, 0);
            }
        }
        __syncthreads();
    }

    int orow = row0 + wrow * 16 + quad * 4;
    if (DOT) {
        float dp[4] = {0.f, 0.f, 0.f, 0.f};
#pragma unroll
        for (int t = 0; t < 4; t++) {
            int col = col0 + (wcol * 4 + t) * 16 + lrow;
            float hw = head_w[col];
            float bv = bias[col];
#pragma unroll
            for (int r = 0; r < 4; r++)
                dp[r] += gelu_exact(acc[t][r] + bv) * hw;
        }
#pragma unroll
        for (int r = 0; r < 4; r++) {
#pragma unroll
            for (int off = 1; off < 16; off <<= 1)
                dp[r] += __shfl_xor(dp[r], off, 64);
        }
        if (lrow == 0) {
#pragma unroll
            for (int r = 0; r < 4; r++) atomicAdd(&sdot[orow + r], dp[r]);
        }
    } else {
#pragma unroll
        for (int t = 0; t < 4; t++) {
            int col = col0 + (wcol * 4 + t) * 16 + lrow;
            float bv = bias[col];
#pragma unroll
            for (int r = 0; r < 4; r++)
                C[(size_t)(orow + r) * 256 + col] = (_Float16)gelu_exact(acc[t][r] + bv);
        }
    }
}

// Per-node summaries from fp16 m: P1, P2, Q1, Q2 (12 floats/node)
__global__ __launch_bounds__(256)
void node_summary_kernel(const _Float16* __restrict__ m, const float* __restrict__ cw,
                         float* __restrict__ ns) {
    __shared__ __align__(16) float4 s_cw[512];
    int tid = threadIdx.x;
    for (int i = tid; i < 512; i += 256) s_cw[i] = *(const float4*)&cw[(size_t)i * 4];
    __syncthreads();
    int n = blockIdx.x * 4 + (tid >> 6);
    if (n >= N_NODES) return;
    int lane = tid & 63;
    f16x4 a4 = *(const f16x4*)&m[(size_t)n * CDIM + lane * 4];
    float av[4] = {(float)a4[0], (float)a4[1], (float)a4[2], (float)a4[3]};
    float Q1 = 0.f, Q2 = 0.f, P1[4] = {0, 0, 0, 0}, P2[4] = {0, 0, 0, 0};
#pragma unroll
    for (int j = 0; j < 4; j++) {
        Q1 += av[j];
        Q2 += av[j] * av[j];
        float4 c0 = s_cw[lane * 4 + j];
        float4 c1 = s_cw[256 + lane * 4 + j];
        P1[0] += av[j] * c0.x; P1[1] += av[j] * c0.y; P1[2] += av[j] * c0.z; P1[3] += av[j] * c0.w;
        P2[0] += av[j] * c1.x; P2[1] += av[j] * c1.y; P2[2] += av[j] * c1.z; P2[3] += av[j] * c1.w;
    }
#pragma unroll
    for (int off = 1; off < 64; off <<= 1) {
        Q1 += __shfl_xor(Q1, off, 64);
        Q2 += __shfl_xor(Q2, off, 64);
        P1[0] += __shfl_xor(P1[0], off, 64);
        P1[1] += __shfl_xor(P1[1], off, 64);
        P1[2] += __shfl_xor(P1[2], off, 64);
        P1[3] += __shfl_xor(P1[3], off, 64);
        P2[0] += __shfl_xor(P2[0], off, 64);
        P2[1] += __shfl_xor(P2[1], off, 64);
        P2[2] += __shfl_xor(P2[2], off, 64);
        P2[3] += __shfl_xor(P2[3], off, 64);
    }
    if (lane == 0) {
        float* p = &ns[(size_t)n * 12];
        *(float4*)p = make_float4(P1[0], P1[1], P1[2], P1[3]);
        *(float4*)(p + 4) = make_float4(P2[0], P2[1], P2[2], P2[3]);
        p[8] = Q1;
        p[9] = Q2;
    }
}

// One thread per edge: edge MLP from node summaries; writes w into CSR slot.
__global__ __launch_bounds__(256)
void edge_weight_kernel(const float* __restrict__ ns, const float* __restrict__ x_pos,
                        const int* __restrict__ ei, const float* __restrict__ cw,
                        const float* __restrict__ SgSb, const float* __restrict__ w1_b,
                        const float* __restrict__ ln2_g, const float* __restrict__ ln2_b,
                        const float* __restrict__ w2_w, const float* __restrict__ w2_b,
                        const int* __restrict__ slot, float* __restrict__ w_csr) {
    int e = blockIdx.x * 256 + threadIdx.x;
    if (e >= N_EDGES) return;
    int s = ei[e], d = ei[N_EDGES + e];
    const float* nss = &ns[(size_t)s * 12];
    const float* nsd = &ns[(size_t)d * 12];
    float4 p1 = *(const float4*)nss;
    float4 p2 = *(const float4*)(nsd + 4);
    float S1 = nss[8] + nsd[8];
    float S2 = nss[9] + nsd[9];
    float D[4] = {p1.x + p2.x, p1.y + p2.y, p1.z + p2.z, p1.w + p2.w};
    float ps[6];
    ps[0] = x_pos[(size_t)s * 3 + 0];
    ps[1] = x_pos[(size_t)s * 3 + 1];
    ps[2] = x_pos[(size_t)s * 3 + 2];
    ps[3] = x_pos[(size_t)d * 3 + 0];
    ps[4] = x_pos[(size_t)d * 3 + 1];
    ps[5] = x_pos[(size_t)d * 3 + 2];
#pragma unroll
    for (int k = 0; k < 6; k++) {
        S1 += ps[k];
        S2 += ps[k] * ps[k];
        float4 c = *(const float4*)&cw[(size_t)(512 + k) * 4];
        D[0] += ps[k] * c.x; D[1] += ps[k] * c.y; D[2] += ps[k] * c.z; D[3] += ps[k] * c.w;
    }
    const float inv = 1.f / 518.f;
    float mu = S1 * inv;
    float var = fmaf(-mu, mu, S2 * inv);
    float rstd = rsqrtf(var + LN_EPS);
    float t[4];
#pragma unroll
    for (int c = 0; c < 4; c++)
        t[c] = gelu_exact(rstd * (D[c] - mu * SgSb[c]) + SgSb[4 + c] + w1_b[c]);
    float mu2 = 0.25f * (t[0] + t[1] + t[2] + t[3]);
    float var2 = 0.25f * ((t[0] - mu2) * (t[0] - mu2) + (t[1] - mu2) * (t[1] - mu2) +
                          (t[2] - mu2) * (t[2] - mu2) + (t[3] - mu2) * (t[3] - mu2));
    float r2 = rsqrtf(var2 + LN_EPS);
    float z = w2_b[0];
#pragma unroll
    for (int c = 0; c < 4; c++)
        z += ((t[c] - mu2) * r2 * ln2_g[c] + ln2_b[c]) * w2_w[c];
    w_csr[slot[e]] = 1.f / (1.f + expf(-z));
}

// CSR SpMM over fp16 m, unrolled x8 for memory-level parallelism.
__global__ __launch_bounds__(256)
void agg_kernel(const _Float16* __restrict__ m, const int* __restrict__ csr_src,
                const float* __restrict__ w_csr, const int* __restrict__ row_start,
                _Float16* __restrict__ agg) {
    int n = blockIdx.x * 4 + (threadIdx.x >> 6);
    if (n >= N_NODES) return;
    int lane = threadIdx.x & 63;
    int beg = row_start[n], end = row_start[n + 1];
    float a0 = 0.f, a1 = 0.f, a2 = 0.f, a3 = 0.f;
    int j = beg;
    for (; j + 8 <= end; j += 8) {
        int si[8];
        float wi[8];
#pragma unroll
        for (int u = 0; u < 8; u++) { si[u] = csr_src[j + u]; wi[u] = w_csr[j + u]; }
        f16x4 v[8];
#pragma unroll
        for (int u = 0; u < 8; u++) v[u] = *(const f16x4*)&m[(size_t)si[u] * CDIM + lane * 4];
#pragma unroll
        for (int u = 0; u < 8; u++) {
            a0 = fmaf(wi[u], (float)v[u][0], a0);
            a1 = fmaf(wi[u], (float)v[u][1], a1);
            a2 = fmaf(wi[u], (float)v[u][2], a2);
            a3 = fmaf(wi[u], (float)v[u][3], a3);
        }
    }
    for (; j < end; j++) {
        int s = csr_src[j];
        float w = w_csr[j];
        f16x4 v = *(const f16x4*)&m[(size_t)s * CDIM + lane * 4];
        a0 = fmaf(w, (float)v[0], a0);
        a1 = fmaf(w, (float)v[1], a1);
        a2 = fmaf(w, (float)v[2], a2);
        a3 = fmaf(w, (float)v[3], a3);
    }
    f16x4 o;
    o[0] = (_Float16)a0; o[1] = (_Float16)a1; o[2] = (_Float16)a2; o[3] = (_Float16)a3;
    *(f16x4*)&agg[(size_t)n * CDIM + lane * 4] = o;
}

__global__ __launch_bounds__(256)
void final_head_kernel(const float* __restrict__ sdot, const int* __restrict__ gstart,
                       const float* __restrict__ head_b, float* __restrict__ out) {
    int g = blockIdx.x;
    int t = threadIdx.x;
    int beg = gstart[g], end = gstart[g + 1];
    float s = 0.f;
    for (int i = beg + t; i < end; i += 256) s += sdot[i];
    __shared__ float red[256];
    red[t] = s;
    __syncthreads();
    for (int k = 128; k > 0; k >>= 1) {
        if (t < k) red[t] += red[t + k];
        __syncthreads();
    }
    if (t == 0) out[g] = red[0] / fmaxf((float)(end - beg), 1.f) + head_b[0];
}

extern "C" void kernel_launch(void* const* d_in, const int* in_sizes, int n_in,
                              void* d_out, int out_size, void* d_ws, size_t ws_size,
                              hipStream_t stream) {
    const float* x       = (const float*)d_in[0];
    const float* x_pos   = (const float*)d_in[1];
    const int*   ei      = (const int*)d_in[2];
    const int*   batch   = (const int*)d_in[3];
    const float* dense_w = (const float*)d_in[4];
    const float* dense_b = (const float*)d_in[5];
    const float* d1_w    = (const float*)d_in[6];
    const float* d1_b    = (const float*)d_in[7];
    const float* ln1_g   = (const float*)d_in[8];
    const float* ln1_b   = (const float*)d_in[9];
    const float* w1_w    = (const float*)d_in[10];
    const float* w1_b    = (const float*)d_in[11];
    const float* ln2_g   = (const float*)d_in[12];
    const float* ln2_b   = (const float*)d_in[13];
    const float* w2_w    = (const float*)d_in[14];
    const float* w2_b    = (const float*)d_in[15];
    const float* d2_w    = (const float*)d_in[16];
    const float* d2_b    = (const float*)d_in[17];
    const float* head_w  = (const float*)d_in[18];
    const float* head_b  = (const float*)d_in[19];
    float* out = (float*)d_out;

    _Float16* hbuf0 = (_Float16*)d_ws;                          // [N][256] fp16
    _Float16* hbuf1 = hbuf0 + (size_t)N_NODES * CDIM;           // [N][256] fp16
    _Float16* wt_dense = hbuf1 + (size_t)N_NODES * CDIM;        // [256][768] fp16
    _Float16* wt_sq    = wt_dense + (size_t)256 * KPAD_DENSE;   // [8][256][256] fp16
    float* cw    = (float*)(wt_sq + (size_t)8 * 256 * 256);     // [L][518][4]
    float* SgSb  = cw + (size_t)NLAYERS * ED_DIM * 4;           // [L][8]
    float* ns    = SgSb + NLAYERS * 8;                          // [N][12]
    float* sdot  = ns + (size_t)N_NODES * 12;                   // [N]
    float* w_csr = sdot + N_NODES;                              // [E]
    int* gstart    = (int*)(w_csr + N_EDGES);                   // [33]
    int* deg       = gstart + N_GRAPHS + 1;                     // [N]
    int* row_start = deg + N_NODES;                             // [N+1]
    int* cursor    = row_start + N_NODES + 1;                   // [N]
    int* csr_src   = cursor + N_NODES;                          // [E]
    int* slot      = csr_src + N_EDGES;                         // [E]
    int* bsum      = slot + N_EDGES;                            // [SCAN_BLOCKS]
    int* boff      = bsum + SCAN_BLOCKS;                        // [SCAN_BLOCKS]

    prep_all<<<866, 256, 0, stream>>>(ln1_g, ln1_b, w1_w, cw, SgSb,
                                      dense_w, wt_dense, d1_w, d2_w, wt_sq, deg, sdot);

    hist_gstart_kernel<<<(N_EDGES + 255) / 256, 256, 0, stream>>>(ei, batch, deg, gstart);
    scan1_kernel<<<SCAN_BLOCKS, 256, 0, stream>>>(deg, bsum);
    scan2_kernel<<<1, 128, 0, stream>>>(bsum, boff);
    scan3_kernel<<<SCAN_BLOCKS, 256, 0, stream>>>(deg, boff, row_start, cursor);
    scatter_kernel<<<(N_EDGES + 255) / 256, 256, 0, stream>>>(ei, cursor, csr_src, slot);

    const dim3 GGRID(N_NODES / 32, 2);  // (625, 2) = 1250 blocks
    gemm_dense<<<GGRID, 256, 0, stream>>>(x, wt_dense, dense_b, hbuf0);

    _Float16* h = hbuf0;
    _Float16* other = hbuf1;
    for (int l = 0; l < NLAYERS; l++) {
        gemm_mfma<false><<<GGRID, 256, 0, stream>>>(
            h, wt_sq + (size_t)l * 65536, d1_b + l * CDIM, other, nullptr, nullptr);
        node_summary_kernel<<<(N_NODES + 3) / 4, 256, 0, stream>>>(
            other, cw + (size_t)l * ED_DIM * 4, ns);
        edge_weight_kernel<<<(N_EDGES + 255) / 256, 256, 0, stream>>>(
            ns, x_pos, ei, cw + (size_t)l * ED_DIM * 4, SgSb + l * 8, w1_b + l * 4,
            ln2_g + l * 4, ln2_b + l * 4, w2_w + l * 4, w2_b + l, slot, w_csr);
        agg_kernel<<<(N_NODES + 3) / 4, 256, 0, stream>>>(other, csr_src, w_csr, row_start, h);
        if (l < NLAYERS - 1) {
            gemm_mfma<false><<<GGRID, 256, 0, stream>>>(
                h, wt_sq + (size_t)(4 + l) * 65536, d2_b + l * CDIM, other, nullptr, nullptr);
        } else {
            gemm_mfma<true><<<GGRID, 256, 0, stream>>>(
                h, wt_sq + (size_t)(4 + l) * 65536, d2_b + l * CDIM, other, head_w, sdot);
        }
        _Float16* tmp = h; h = other; other = tmp;
    }

    final_head_kernel<<<N_GRAPHS, 256, 0, stream>>>(sdot, gstart, head_b, out);
}